// Round 1
// baseline (247.460 us; speedup 1.0000x reference)
//
#include <hip/hip_runtime.h>

// CRF forward loss, MI355X. One block per batch (128 blocks, 512 threads).
// Lanes = tag j (48 of 64 active); 8 waves split the i-reduction (6 i's each).
// All math in log2 domain (v_exp_f32 / v_log_f32 are base-2 natively).

constexpr int SEQ = 256;
constexpr int NTAG = 48;
constexpr int START_TAG = 46;
constexpr int END_TAG = 47;
constexpr float SENT = -100000.0f;          // sentinel, assigned (never computed)
constexpr float L2E  = 1.4426950408889634f; // log2(e)
constexpr float LN2  = 0.6931471805599453f;
constexpr int W = 8;   // waves per block
constexpr int C = 6;   // i-chunk per wave (W*C == NTAG)

__device__ __forceinline__ float fexp2(float x) { return __builtin_amdgcn_exp2f(x); }
__device__ __forceinline__ float flog2(float x) { return __builtin_amdgcn_logf(x); }

__global__ __launch_bounds__(W * 64)
void crf_fwd_kernel(const float* __restrict__ S,
                    const void* __restrict__ tgtv,
                    const void* __restrict__ mskv,
                    float* __restrict__ ws)
{
    const int b    = blockIdx.x;
    const int tid  = threadIdx.x;
    const int k    = tid >> 6;      // wave id
    const int j    = tid & 63;      // lane = tag column
    const int i0   = k * C;         // this wave's i-chunk start
    const bool jok = (j < NTAG);

    // --- dtype detection: bool-packed (1B) vs int32 targets/mask ---
    // mask[0][0..3] are all 1 (len >= 128). int32 -> 1; packed bytes -> 0x01010101.
    const bool pack8 = (((const int*)mskv)[0] != 1);
    const unsigned char* msk8  = (const unsigned char*)mskv;
    const int*           msk32 = (const int*)mskv;
    const unsigned char* tgt8  = (const unsigned char*)tgtv;
    const int*           tgt32 = (const int*)tgtv;

    // --- sequence length: popcount of mask row (mask is monotone) ---
    int mv = 0;
    if (tid < SEQ)
        mv = pack8 ? (msk8[(size_t)b * SEQ + tid] != 0)
                   : (msk32[(size_t)b * SEQ + tid] != 0);
    const int len = __syncthreads_count(mv);

    __shared__ float2 s_state[NTAG];        // (partition, tag_partition), log2 domain
    __shared__ float  s_mp[W][NTAG];        // partial max, partition
    __shared__ float  s_sp[W][NTAG];        // partial sum, partition
    __shared__ float  s_mt[W][NTAG];        // partial max, tag_partition
    __shared__ float  s_st[W][NTAG];        // partial sum, tag_partition

    const size_t sb = (size_t)b * SEQ * NTAG * NTAG;
    const float* Sp = S + sb + (size_t)i0 * NTAG + j;   // + t*2304 + c*48

    // --- init t = 0 (wave 0): p0 = scores[b,0,START,j]*L2E ---
    if (k == 0 && jok) {
        float p0 = S[sb + START_TAG * NTAG + j] * L2E;
        size_t ti = (size_t)b * SEQ * NTAG + j;
        int tv0 = pack8 ? (int)tgt8[ti] : tgt32[ti];
        s_state[j] = make_float2(p0, tv0 ? SENT : p0);
    }

    // --- preload t=1 -> A, t=2 -> B (len >= 128 so both valid) ---
    float A[C] = {0.f}, Bv[C] = {0.f}, Cv[C] = {0.f};
    if (jok) {
        #pragma unroll
        for (int c = 0; c < C; ++c) A[c] = Sp[(size_t)1 * 2304 + c * NTAG];
        #pragma unroll
        for (int c = 0; c < C; ++c) Bv[c] = Sp[(size_t)2 * 2304 + c * NTAG];
    }
    __syncthreads();

    auto body = [&](float (&sc)[C], float (&ld)[C], int t) {
        // prefetch scores for t+2 (depth-2 in flight)
        const int tl = t + 2;
        if (jok && tl < len) {
            #pragma unroll
            for (int c = 0; c < C; ++c) ld[c] = Sp[(size_t)tl * 2304 + c * NTAG];
        }
        // prefetch target[t][j] (only wave 1 consumes it, in the combine)
        int tv = 0;
        if (k == 1 && jok) {
            size_t ti = ((size_t)b * SEQ + t) * NTAG + j;
            tv = pack8 ? (int)tgt8[ti] : tgt32[ti];
        }

        // a[i] = score[t,i,j]*L2E + state[i]  (both states)
        float ap[C], at[C];
        #pragma unroll
        for (int c = 0; c < C; ++c) {
            float2 st = s_state[i0 + c];         // LDS broadcast read
            ap[c] = fmaf(sc[c], L2E, st.x);
            at[c] = fmaf(sc[c], L2E, st.y);
        }
        float mp = ap[0], mt = at[0];
        #pragma unroll
        for (int c = 1; c < C; ++c) { mp = fmaxf(mp, ap[c]); mt = fmaxf(mt, at[c]); }
        float sp = 0.f, stt = 0.f;
        #pragma unroll
        for (int c = 0; c < C; ++c) {
            sp  += fexp2(ap[c] - mp);
            stt += fexp2(at[c] - mt);
        }
        if (jok) {
            s_mp[k][j] = mp; s_sp[k][j] = sp;
            s_mt[k][j] = mt; s_st[k][j] = stt;
        }
        __syncthreads();

        // combine W partials: wave0 -> partition, wave1 -> tag_partition
        if (k < 2 && jok) {
            float m[W], s[W];
            if (k == 0) {
                #pragma unroll
                for (int q = 0; q < W; ++q) { m[q] = s_mp[q][j]; s[q] = s_sp[q][j]; }
            } else {
                #pragma unroll
                for (int q = 0; q < W; ++q) { m[q] = s_mt[q][j]; s[q] = s_st[q][j]; }
            }
            float M = m[0];
            #pragma unroll
            for (int q = 1; q < W; ++q) M = fmaxf(M, m[q]);
            float Ssum = 0.f;
            #pragma unroll
            for (int q = 0; q < W; ++q) Ssum = fmaf(s[q], fexp2(m[q] - M), Ssum);
            float np = M + flog2(Ssum);
            if (k == 1 && tv) np = SENT;         // target mask (assigned sentinel)
            ((float*)s_state)[j * 2 + k] = np;
        }
        __syncthreads();
    };

    // 3-buffer rotation, manually unrolled (static register indices)
    for (int t = 1; t < len; t += 3) {
        body(A, Cv, t);
        if (t + 1 < len) body(Bv, A, t + 1);
        if (t + 2 < len) body(Cv, Bv, t + 2);
    }

    if (tid == 0) {
        float2 fin = s_state[END_TAG];
        float pe = fin.x * LN2;
        float te = (fin.y == SENT) ? 0.f : fin.y * LN2;
        ws[b] = pe - te;
    }
}

__global__ void crf_reduce_kernel(const float* __restrict__ ws, float* __restrict__ out)
{
    int l = threadIdx.x;                 // 64 threads
    float v = ws[l] + ws[l + 64];
    #pragma unroll
    for (int off = 32; off > 0; off >>= 1) v += __shfl_down(v, off);
    if (l == 0) out[0] = v;
}

extern "C" void kernel_launch(void* const* d_in, const int* in_sizes, int n_in,
                              void* d_out, int out_size, void* d_ws, size_t ws_size,
                              hipStream_t stream)
{
    const float* S   = (const float*)d_in[0];
    const void*  tgt = d_in[1];
    const void*  msk = d_in[2];
    float* out = (float*)d_out;
    float* ws  = (float*)d_ws;

    crf_fwd_kernel<<<128, W * 64, 0, stream>>>(S, tgt, msk, ws);
    crf_reduce_kernel<<<1, 64, 0, stream>>>(ws, out);
}